// Round 5
// baseline (3928.197 us; speedup 1.0000x reference)
//
#include <hip/hip_runtime.h>

#define N_USERS 20000
#define N_ITEMS 20000
#define NI1     20001      // row stride (elements) of interactions
#define HB      4096       // batch
#define H0      256
#define H1      512
#define H2      256

typedef unsigned short u16;
typedef unsigned char  u8;
typedef unsigned int   u32;
typedef unsigned long long u64;

typedef __attribute__((ext_vector_type(8))) __bf16 bf16x8;
typedef __attribute__((ext_vector_type(4))) float  f32x4;

__device__ __forceinline__ u16 f2bf(float f) {
  u32 u = __float_as_uint(f);
  u32 r = (u + 0x7FFFu + ((u >> 16) & 1u)) >> 16;   // RNE
  return (u16)r;
}

// ---------------- detect interactions element layout ----------------
// 0 = 1-byte bool, 1 = int32, 2 = float32 (classify by nonzero byte offsets)
__global__ __launch_bounds__(256) void k_detect(const u8* __restrict__ inter,
                                                int* __restrict__ flag) {
  __shared__ u32 cnt[4];
  if (threadIdx.x < 4) cnt[threadIdx.x] = 0;
  __syncthreads();
  u32 loc0 = 0, loc1 = 0, loc2 = 0, loc3 = 0;
  for (int i = threadIdx.x; i < 16384; i += 256) {   // 64 KB scan
    u32 w = ((const u32*)inter)[i];
    loc0 += (w & 0x000000FFu) ? 1u : 0u;
    loc1 += (w & 0x0000FF00u) ? 1u : 0u;
    loc2 += (w & 0x00FF0000u) ? 1u : 0u;
    loc3 += (w & 0xFF000000u) ? 1u : 0u;
  }
  atomicAdd(&cnt[0], loc0); atomicAdd(&cnt[1], loc1);
  atomicAdd(&cnt[2], loc2); atomicAdd(&cnt[3], loc3);
  __syncthreads();
  if (threadIdx.x == 0) {
    int lay;
    if (cnt[1] != 0)      lay = 0;   // bytes populated at offset1 -> u8 bool
    else if (cnt[0] != 0) lay = 1;   // only offset0 -> little-endian int32
    else                  lay = 2;   // offsets 2/3 only -> float32 (0x3F800000)
    *flag = lay;
  }
}

// element load: 0/nonzero per layout
template <int LAY>
__device__ __forceinline__ u32 ld_one(const u8* __restrict__ inter, long idx) {
  if (LAY == 0) return inter[idx];
  return ((const u32*)inter)[idx];   // int32 or f32: nonzero bits <=> true
}

// ---------------- f32 -> bf16 copy-convert (keeps layout) ----------------
__global__ __launch_bounds__(256) void k_convert(const float* __restrict__ in,
                                                 u16* __restrict__ out, int n4) {
  int idx = blockIdx.x * 256 + threadIdx.x;
  int stride = gridDim.x * 256;
  for (int i = idx; i < n4; i += stride) {
    float4 v = ((const float4*)in)[i];
    u64 p = (u64)f2bf(v.x) | ((u64)f2bf(v.y) << 16) |
            ((u64)f2bf(v.z) << 32) | ((u64)f2bf(v.w) << 48);
    ((u64*)out)[i] = p;
  }
}

// ---------------- f32 transpose: in (R,C) -> out (C,R) ----------------
__global__ __launch_bounds__(256) void k_transpose(const float* __restrict__ in,
                                                   float* __restrict__ out,
                                                   int R, int C) {
  __shared__ float tile[32][33];
  int nbx = C >> 5;
  int bx = blockIdx.x % nbx, by = blockIdx.x / nbx;
  int c0 = bx * 32, r0 = by * 32;
  int lx = threadIdx.x & 31, ly = threadIdx.x >> 5;  // 256 thr: ly 0..7
  #pragma unroll
  for (int j = 0; j < 4; ++j)
    tile[ly + 8*j][lx] = in[(size_t)(r0 + ly + 8*j) * C + c0 + lx];
  __syncthreads();
  #pragma unroll
  for (int j = 0; j < 4; ++j)
    out[(size_t)(c0 + ly + 8*j) * R + r0 + lx] = tile[lx][ly + 8*j];
}

// ---------------- counting sort of batch rows by item_idx ----------------
__global__ __launch_bounds__(1024) void k_sort(const int* __restrict__ item_idx,
                                               int* __restrict__ perm) {
  __shared__ u32 cnt[N_ITEMS];     // 80 KB
  __shared__ u32 tsum[1024];
  int t = threadIdx.x;
  for (int i = t; i < N_ITEMS; i += 1024) cnt[i] = 0;
  __syncthreads();
  for (int b = t; b < HB; b += 1024) atomicAdd(&cnt[item_idx[b]], 1u);
  __syncthreads();
  u32 s = 0;
  int base = t * 20;
  for (int j = 0; j < 20; ++j) { int i = base + j; if (i < N_ITEMS) s += cnt[i]; }
  tsum[t] = s;
  __syncthreads();
  for (int off = 1; off < 1024; off <<= 1) {
    u32 v = (t >= off) ? tsum[t - off] : 0u;
    __syncthreads();
    tsum[t] += v;
    __syncthreads();
  }
  u32 run = tsum[t] - s;  // exclusive prefix
  for (int j = 0; j < 20; ++j) {
    int i = base + j;
    if (i < N_ITEMS) { u32 c = cnt[i]; cnt[i] = run; run += c; }
  }
  __syncthreads();
  for (int b = t; b < HB; b += 1024) {
    int v = item_idx[b];
    u32 pos = atomicAdd(&cnt[v], 1u);
    perm[pos] = b;
  }
}

// ---------------- fused binary-gather GEMM (bf16 MFMA) ----------------
// blocks 0..127: user mode  C=u0:  A[b][k] = inter[user_idx[b]*NI1 + k]
// blocks 128..255: item mode C=ir: A[s][k] = inter[k*NI1 + item_idx[perm[s]]]
// tile: 128 (M) x 64 (N), BK=64; 4 waves (2x2), each 64x32 via 16x16x32 MFMA.
template <int LAY>
__global__ __launch_bounds__(256) void k_gemm(
    const u8* __restrict__ inter,
    const int* __restrict__ user_idx, const int* __restrict__ item_idx,
    const int* __restrict__ perm,
    const u16* __restrict__ Wub, const u16* __restrict__ Wib,
    float* __restrict__ u0, float* __restrict__ ir,
    const int* __restrict__ flag) {
  if (*flag != LAY) return;    // device-side layout dispatch

  __shared__ __attribute__((aligned(16))) u16 Als[128 * 64];
  __shared__ __attribute__((aligned(16))) u16 Bls[64 * 64];
  __shared__ long rbase[128];   // user: row element base; item: column index
  __shared__ int  prow[128];    // output row (identity / perm)

  int bid = blockIdx.x;
  int mode_item = bid >> 7;
  int lid = bid & 127;
  int M0 = (lid >> 2) * 128;
  int N0 = (lid & 3) * 64;
  int tid = threadIdx.x;
  const u16* Wb = mode_item ? Wib : Wub;
  float* Cout = mode_item ? ir : u0;

  if (tid < 128) {
    int s = M0 + tid;
    if (mode_item) { int p = perm[s]; prow[tid] = p; rbase[tid] = item_idx[p]; }
    else           { prow[tid] = s;   rbase[tid] = (long)user_idx[s] * NI1; }
  }
  __syncthreads();

  f32x4 acc[4][2];
  #pragma unroll
  for (int a = 0; a < 4; ++a)
    #pragma unroll
    for (int b = 0; b < 2; ++b)
      #pragma unroll
      for (int j = 0; j < 4; ++j) acc[a][b][j] = 0.f;

  int lane = tid & 63;
  int wave = tid >> 6;
  int WM = (wave >> 1) * 64;
  int WN = (wave & 1) * 32;
  int lrow = lane & 15;
  int lkb = (lane >> 4) * 8;

  for (int k0 = 0; k0 < N_ITEMS; k0 += 64) {
    // ---- stage A (elements -> bf16 0/1, XOR-swizzled LDS) ----
    if (!mode_item) {
      #pragma unroll
      for (int i = 0; i < 16; ++i) {
        int id = tid + 256 * i;          // 4096 pair-ids
        int r = id >> 5, c2 = id & 31;   // row, pair-col
        int k = k0 + c2 * 2;
        long base = rbase[r];
        u32 v0 = (k     < N_ITEMS && ld_one<LAY>(inter, base + k    )) ? 0x3F80u : 0u;
        u32 v1 = (k + 1 < N_ITEMS && ld_one<LAY>(inter, base + k + 1)) ? 0x3F80u : 0u;
        int off = r * 64 + ((c2 * 2) ^ ((r & 7) << 3));
        *(u32*)&Als[off] = v0 | (v1 << 16);
      }
    } else {
      #pragma unroll
      for (int i = 0; i < 16; ++i) {
        int id = tid + 256 * i;
        int r = id & 127, c2 = id >> 7;  // lanes vary r -> clustered (sorted) cols
        int k = k0 + c2 * 2;
        long col = rbase[r];
        u32 v0 = (k     < N_ITEMS && ld_one<LAY>(inter, (long)k * NI1 + col)) ? 0x3F80u : 0u;
        u32 v1 = (k + 1 < N_ITEMS && ld_one<LAY>(inter, (long)(k + 1) * NI1 + col)) ? 0x3F80u : 0u;
        int off = r * 64 + ((c2 * 2) ^ ((r & 7) << 3));
        *(u32*)&Als[off] = v0 | (v1 << 16);
      }
    }
    // ---- stage B: B_lds[n][k] = W[n][k] (layout already (H0, 20000)) ----
    #pragma unroll
    for (int i = 0; i < 4; ++i) {
      int id = tid + 256 * i;          // 1024 quad-ids
      int n = id >> 4, c4 = id & 15;
      int k = k0 + c4 * 4;
      uint2 v = make_uint2(0u, 0u);
      if (k + 3 < N_ITEMS) v = *(const uint2*)&Wb[(size_t)(N0 + n) * N_ITEMS + k];
      int off = n * 64 + ((c4 * 4) ^ ((n & 7) << 3));
      *(uint2*)&Bls[off] = v;
    }
    __syncthreads();
    // ---- MFMA ----
    #pragma unroll
    for (int kk = 0; kk < 64; kk += 32) {
      bf16x8 af[4], bfr[2];
      #pragma unroll
      for (int fm = 0; fm < 4; ++fm) {
        int r = WM + fm * 16 + lrow;
        af[fm] = *(const bf16x8*)&Als[r * 64 + ((kk + lkb) ^ ((r & 7) << 3))];
      }
      #pragma unroll
      for (int fn = 0; fn < 2; ++fn) {
        int n = WN + fn * 16 + lrow;
        bfr[fn] = *(const bf16x8*)&Bls[n * 64 + ((kk + lkb) ^ ((n & 7) << 3))];
      }
      #pragma unroll
      for (int fm = 0; fm < 4; ++fm)
        #pragma unroll
        for (int fn = 0; fn < 2; ++fn)
          acc[fm][fn] = __builtin_amdgcn_mfma_f32_16x16x32_bf16(
              af[fm], bfr[fn], acc[fm][fn], 0, 0, 0);
    }
    __syncthreads();
  }

  // ---- epilogue: C/D layout col=lane&15, row=(lane>>4)*4+j ----
  int crow0 = (lane >> 4) * 4;
  int ccol = lane & 15;
  #pragma unroll
  for (int fm = 0; fm < 4; ++fm)
    #pragma unroll
    for (int fn = 0; fn < 2; ++fn) {
      f32x4 v = acc[fm][fn];
      int col = N0 + WN + fn * 16 + ccol;
      #pragma unroll
      for (int j = 0; j < 4; ++j) {
        int rl = WM + fm * 16 + crow0 + j;
        int orow = prow[rl];
        Cout[(size_t)orow * H0 + col] = v[j];
      }
    }
}

// ---------------- fused correction + MLP + LN + logit ----------------
__global__ __launch_bounds__(256) void k_mlp(
    const u8* __restrict__ inter,
    const int* __restrict__ user_idx, const int* __restrict__ item_idx,
    const float* __restrict__ Wu, const float* __restrict__ Wi,
    const float* __restrict__ u0, const float* __restrict__ ir,
    const float* __restrict__ W1T, const float* __restrict__ b1,
    const float* __restrict__ g1, const float* __restrict__ be1,
    const float* __restrict__ W2T, const float* __restrict__ b2,
    const float* __restrict__ g2, const float* __restrict__ be2,
    const float* __restrict__ Wl, const float* __restrict__ bl,
    const int* __restrict__ flag,
    float* __restrict__ out) {
  __shared__ __attribute__((aligned(16))) float xl[16][H0];   // u0 tile, later ur tile
  __shared__ __attribute__((aligned(16))) float h1l[16][H1];
  __shared__ int flagL[16], uL[16], iL[16];

  int tid = threadIdx.x, lane = tid & 63, wave = tid >> 6;
  int b0 = blockIdx.x * 16;

  if (tid < 16) {
    int b = b0 + tid;
    int uu = user_idx[b], ii = item_idx[b];
    uL[tid] = uu; iL[tid] = ii;
    long idx = (long)uu * NI1 + ii;
    int lay = *flag;
    u32 v = (lay == 0) ? (u32)inter[idx] : ((const u32*)inter)[idx];
    flagL[tid] = v ? 1 : 0;
  }
  __syncthreads();

  // load u0 tile + target-item correction
  for (int idx = tid; idx < 16 * H0; idx += 256) {
    int rr = idx >> 8, h = idx & 255;
    float x = u0[(size_t)(b0 + rr) * H0 + h];
    if (flagL[rr]) x -= Wu[(size_t)h * N_ITEMS + iL[rr]];
    xl[rr][h] = x;
  }
  __syncthreads();

  // ---- layer1: (16x256) @ W1T(256x512); thread t -> cols t, t+256 ----
  float a0[16], a1[16];
  #pragma unroll
  for (int rr = 0; rr < 16; ++rr) { a0[rr] = 0.f; a1[rr] = 0.f; }
  for (int k4 = 0; k4 < H0 / 4; ++k4) {
    int k = k4 * 4;
    float w0a = W1T[(size_t)(k+0)*H1 + tid], w0b = W1T[(size_t)(k+0)*H1 + tid + 256];
    float w1a = W1T[(size_t)(k+1)*H1 + tid], w1b = W1T[(size_t)(k+1)*H1 + tid + 256];
    float w2a = W1T[(size_t)(k+2)*H1 + tid], w2b = W1T[(size_t)(k+2)*H1 + tid + 256];
    float w3a = W1T[(size_t)(k+3)*H1 + tid], w3b = W1T[(size_t)(k+3)*H1 + tid + 256];
    #pragma unroll
    for (int rr = 0; rr < 16; ++rr) {
      float4 x = *(const float4*)&xl[rr][k];
      a0[rr] += x.x * w0a + x.y * w1a + x.z * w2a + x.w * w3a;
      a1[rr] += x.x * w0b + x.y * w1b + x.z * w2b + x.w * w3b;
    }
  }
  #pragma unroll
  for (int rr = 0; rr < 16; ++rr) {
    h1l[rr][tid]       = a0[rr] + b1[tid];
    h1l[rr][tid + 256] = a1[rr] + b1[tid + 256];
  }
  __syncthreads();

  // LN1 + relu (wave per row, wave-local reduce)
  for (int rr = wave; rr < 16; rr += 4) {
    float s = 0.f;
    #pragma unroll
    for (int j = 0; j < 8; ++j) s += h1l[rr][lane + 64 * j];
    #pragma unroll
    for (int off = 32; off; off >>= 1) s += __shfl_xor(s, off);
    float m = s * (1.f / H1);
    float v = 0.f;
    #pragma unroll
    for (int j = 0; j < 8; ++j) { float d = h1l[rr][lane + 64*j] - m; v += d * d; }
    #pragma unroll
    for (int off = 32; off; off >>= 1) v += __shfl_xor(v, off);
    float inv = rsqrtf(v * (1.f / H1) + 1e-5f);
    #pragma unroll
    for (int j = 0; j < 8; ++j) {
      int o = lane + 64 * j;
      float y = (h1l[rr][o] - m) * inv * g1[o] + be1[o];
      h1l[rr][o] = fmaxf(y, 0.f);
    }
  }
  __syncthreads();

  // ---- layer2: (16x512) @ W2T(512x256); thread t -> col t ----
  float a2[16];
  #pragma unroll
  for (int rr = 0; rr < 16; ++rr) a2[rr] = 0.f;
  for (int k4 = 0; k4 < H1 / 4; ++k4) {
    int k = k4 * 4;
    float w0 = W2T[(size_t)(k+0)*H2 + tid];
    float w1 = W2T[(size_t)(k+1)*H2 + tid];
    float w2 = W2T[(size_t)(k+2)*H2 + tid];
    float w3 = W2T[(size_t)(k+3)*H2 + tid];
    #pragma unroll
    for (int rr = 0; rr < 16; ++rr) {
      float4 x = *(const float4*)&h1l[rr][k];
      a2[rr] += x.x * w0 + x.y * w1 + x.z * w2 + x.w * w3;
    }
  }
  __syncthreads();   // xl reads (layer1) are long done; reuse xl for ur
  #pragma unroll
  for (int rr = 0; rr < 16; ++rr) xl[rr][tid] = a2[rr] + b2[tid];
  __syncthreads();

  // LN2 + relu
  for (int rr = wave; rr < 16; rr += 4) {
    float s = 0.f;
    #pragma unroll
    for (int j = 0; j < 4; ++j) s += xl[rr][lane + 64 * j];
    #pragma unroll
    for (int off = 32; off; off >>= 1) s += __shfl_xor(s, off);
    float m = s * (1.f / H2);
    float v = 0.f;
    #pragma unroll
    for (int j = 0; j < 4; ++j) { float d = xl[rr][lane + 64*j] - m; v += d * d; }
    #pragma unroll
    for (int off = 32; off; off >>= 1) v += __shfl_xor(v, off);
    float inv = rsqrtf(v * (1.f / H2) + 1e-5f);
    #pragma unroll
    for (int j = 0; j < 4; ++j) {
      int o = lane + 64 * j;
      float y = (xl[rr][o] - m) * inv * g2[o] + be2[o];
      xl[rr][o] = fmaxf(y, 0.f);
    }
  }
  __syncthreads();

  // ---- logit: sum_h ur[h] * (ir[h] - corr) * Wl[h] + bl ----
  for (int rr = wave; rr < 16; rr += 4) {
    int b = b0 + rr;
    int flg = flagL[rr], uu = uL[rr];
    float s = 0.f;
    #pragma unroll
    for (int j = 0; j < 4; ++j) {
      int h = lane + 64 * j;
      float irv = ir[(size_t)b * H0 + h];
      if (flg) irv -= Wi[(size_t)h * N_USERS + uu];
      s += xl[rr][h] * irv * Wl[h];
    }
    #pragma unroll
    for (int off = 32; off; off >>= 1) s += __shfl_xor(s, off);
    if (lane == 0) out[b] = s + bl[0];
  }
}

extern "C" void kernel_launch(void* const* d_in, const int* in_sizes, int n_in,
                              void* d_out, int out_size, void* d_ws, size_t ws_size,
                              hipStream_t stream) {
  const int*   user_idx = (const int*)d_in[0];
  const int*   item_idx = (const int*)d_in[1];
  const u8*    inter    = (const u8*)d_in[2];
  const float* Wu  = (const float*)d_in[3];
  const float* Wi  = (const float*)d_in[4];
  const float* W1  = (const float*)d_in[5];
  const float* b1  = (const float*)d_in[6];
  const float* g1  = (const float*)d_in[7];
  const float* be1 = (const float*)d_in[8];
  const float* W2  = (const float*)d_in[9];
  const float* b2  = (const float*)d_in[10];
  const float* g2  = (const float*)d_in[11];
  const float* be2 = (const float*)d_in[12];
  const float* Wl  = (const float*)d_in[13];
  const float* bl  = (const float*)d_in[14];
  float* out = (float*)d_out;

  char* ws = (char*)d_ws;
  size_t off = 0;
  auto alloc = [&](size_t bytes) {
    size_t o = off;
    off = (off + bytes + 255) & ~(size_t)255;
    return o;
  };
  int*   flag = (int*)  (ws + alloc(4));
  u16*   Wub  = (u16*)  (ws + alloc((size_t)H0 * N_ITEMS * 2));
  u16*   Wib  = (u16*)  (ws + alloc((size_t)H0 * N_USERS * 2));
  float* W1T  = (float*)(ws + alloc((size_t)H0 * H1 * 4));
  float* W2T  = (float*)(ws + alloc((size_t)H1 * H2 * 4));
  float* u0   = (float*)(ws + alloc((size_t)HB * H0 * 4));
  float* ir   = (float*)(ws + alloc((size_t)HB * H0 * 4));
  int*   perm = (int*)  (ws + alloc((size_t)HB * 4));

  k_detect<<<1, 256, 0, stream>>>(inter, flag);
  k_convert<<<512, 256, 0, stream>>>(Wu, Wub, (H0 * N_ITEMS) / 4);
  k_convert<<<512, 256, 0, stream>>>(Wi, Wib, (H0 * N_USERS) / 4);
  k_transpose<<<(H1 / 32) * (H0 / 32), 256, 0, stream>>>(W1, W1T, H1, H0);
  k_transpose<<<(H2 / 32) * (H1 / 32), 256, 0, stream>>>(W2, W2T, H2, H1);
  k_sort<<<1, 1024, 0, stream>>>(item_idx, perm);
  k_gemm<0><<<256, 256, 0, stream>>>(inter, user_idx, item_idx, perm, Wub, Wib, u0, ir, flag);
  k_gemm<1><<<256, 256, 0, stream>>>(inter, user_idx, item_idx, perm, Wub, Wib, u0, ir, flag);
  k_gemm<2><<<256, 256, 0, stream>>>(inter, user_idx, item_idx, perm, Wub, Wib, u0, ir, flag);
  k_mlp<<<256, 256, 0, stream>>>(inter, user_idx, item_idx, Wu, Wi, u0, ir,
                                 W1T, b1, g1, be1, W2T, b2, g2, be2, Wl, bl, flag, out);
}

// Round 6
// 1052.380 us; speedup vs baseline: 3.7327x; 3.7327x over previous
//
#include <hip/hip_runtime.h>

#define N_USERS 20000
#define N_ITEMS 20000
#define NI1     20001      // row stride (elements) of interactions
#define HB      4096       // batch
#define H0      256
#define H1      512
#define H2      256
#define PKW     632        // u32 words per packed row (625 data + 7 zero pad)
#define PKB     (PKW*4)    // 2528 bytes per packed row

typedef unsigned short u16;
typedef unsigned char  u8;
typedef unsigned int   u32;
typedef unsigned long long u64;

typedef __attribute__((ext_vector_type(8))) __bf16 bf16x8;
typedef __attribute__((ext_vector_type(4))) float  f32x4;

__device__ __forceinline__ u16 f2bf(float f) {
  u32 u = __float_as_uint(f);
  u32 r = (u + 0x7FFFu + ((u >> 16) & 1u)) >> 16;   // RNE
  return (u16)r;
}

// ---------------- detect interactions element layout ----------------
// 0 = 1-byte bool, 1 = int32, 2 = float32 (classify by nonzero byte offsets)
__global__ __launch_bounds__(256) void k_detect(const u8* __restrict__ inter,
                                                int* __restrict__ flag) {
  __shared__ u32 cnt[4];
  if (threadIdx.x < 4) cnt[threadIdx.x] = 0;
  __syncthreads();
  u32 loc0 = 0, loc1 = 0, loc2 = 0, loc3 = 0;
  for (int i = threadIdx.x; i < 16384; i += 256) {   // 64 KB scan
    u32 w = ((const u32*)inter)[i];
    loc0 += (w & 0x000000FFu) ? 1u : 0u;
    loc1 += (w & 0x0000FF00u) ? 1u : 0u;
    loc2 += (w & 0x00FF0000u) ? 1u : 0u;
    loc3 += (w & 0xFF000000u) ? 1u : 0u;
  }
  atomicAdd(&cnt[0], loc0); atomicAdd(&cnt[1], loc1);
  atomicAdd(&cnt[2], loc2); atomicAdd(&cnt[3], loc3);
  __syncthreads();
  if (threadIdx.x == 0) {
    int lay;
    if (cnt[1] != 0)      lay = 0;   // bytes populated at offset1 -> u8 bool
    else if (cnt[0] != 0) lay = 1;   // only offset0 -> little-endian int32
    else                  lay = 2;   // offsets 2/3 only -> float32 (0x3F800000)
    *flag = lay;
  }
}

// ---------------- bit-pack interactions rows: pk[row][w] ----------------
// wave = one row x 64-word chunk; 64-lane coalesced loads + __ballot.
template <int LAY>
__global__ __launch_bounds__(256) void k_pack(const u8* __restrict__ inter,
                                              u32* __restrict__ pk,
                                              const int* __restrict__ flag) {
  if (*flag != LAY) return;
  int wid = blockIdx.x * 4 + (threadIdx.x >> 6);
  int lane = threadIdx.x & 63;
  int row = wid / 10;
  int chunk = wid - row * 10;
  int w0 = chunk * 64;
  const u8* r8 = inter + (size_t)row * NI1 * (LAY == 0 ? 1 : 4);
  #pragma unroll 4
  for (int it = 0; it < 32; ++it) {
    int w = w0 + it * 2;
    int c = w * 32 + lane;
    bool p;
    if (LAY == 0) p = (c < N_ITEMS) && (r8[c] != 0);
    else          p = (c < N_ITEMS) && (((const u32*)r8)[c] != 0u);
    u64 m = __ballot(p);
    if (lane == 0 && w < PKW)
      *(u64*)&pk[(size_t)row * PKW + w] = m;
  }
}

// ---------------- bit transpose: pkT[c][v] bit j = pk[v*32+j] bit c ----------------
#define HDSTEP(J, M)                                      \
  _Pragma("unroll")                                       \
  for (int k = 0; k < 32; ++k) if (!(k & J)) {            \
    u32 tt = (a[k] ^ (a[k | J] >> J)) & M;                \
    a[k] ^= tt; a[k | J] ^= tt << J;                      \
  }

__global__ __launch_bounds__(256) void k_bitT(const u32* __restrict__ pk,
                                              u32* __restrict__ pkT) {
  __shared__ u32 in_l[512][17];
  __shared__ u32 out_l[512][17];
  int t = threadIdx.x;
  int vt = blockIdx.x % 40, wt = blockIdx.x / 40;
  int v0 = vt * 16, wc0 = wt * 16;     // output words v0..v0+16; input words wc0..wc0+16
  int lw = t & 15, lr = t >> 4;
  // load 512 input rows x 16 words (coalesced 64B clusters)
  for (int ch = 0; ch < 32; ++ch) {
    int rloc = ch * 16 + lr;
    int R = v0 * 32 + rloc;
    int W = wc0 + lw;
    u32 val = 0;
    if (R < N_USERS && W < PKW) val = pk[(size_t)R * PKW + W];
    in_l[rloc][lw] = val;
  }
  __syncthreads();
  // per-thread 32x32 bit transpose: sub-block (v' = lr, wc' = lw)
  u32 a[32];
  #pragma unroll
  for (int j = 0; j < 32; ++j) a[j] = in_l[lr * 32 + j][lw];
  HDSTEP(16, 0x0000FFFFu)
  HDSTEP(8,  0x00FF00FFu)
  HDSTEP(4,  0x0F0F0F0Fu)
  HDSTEP(2,  0x33333333u)
  HDSTEP(1,  0x55555555u)
  // HD yields anti-transpose in LSB convention; true transpose: out[i] = brev(a[31-i])
  #pragma unroll
  for (int i = 0; i < 32; ++i) out_l[lw * 32 + i][lr] = __brev(a[31 - i]);
  __syncthreads();
  for (int ch = 0; ch < 32; ++ch) {
    int rloc = ch * 16 + lr;
    int C = wc0 * 32 + rloc;
    int V = v0 + lw;
    if (C < N_ITEMS && V < PKW)
      pkT[(size_t)C * PKW + V] = out_l[rloc][lw];
  }
}

// ---------------- f32 -> bf16 copy-convert (keeps layout) ----------------
__global__ __launch_bounds__(256) void k_convert(const float* __restrict__ in,
                                                 u16* __restrict__ out, int n4) {
  int idx = blockIdx.x * 256 + threadIdx.x;
  int stride = gridDim.x * 256;
  for (int i = idx; i < n4; i += stride) {
    float4 v = ((const float4*)in)[i];
    u64 p = (u64)f2bf(v.x) | ((u64)f2bf(v.y) << 16) |
            ((u64)f2bf(v.z) << 32) | ((u64)f2bf(v.w) << 48);
    ((u64*)out)[i] = p;
  }
}

// ---------------- f32 transpose: in (R,C) -> out (C,R) ----------------
__global__ __launch_bounds__(256) void k_transpose(const float* __restrict__ in,
                                                   float* __restrict__ out,
                                                   int R, int C) {
  __shared__ float tile[32][33];
  int nbx = C >> 5;
  int bx = blockIdx.x % nbx, by = blockIdx.x / nbx;
  int c0 = bx * 32, r0 = by * 32;
  int lx = threadIdx.x & 31, ly = threadIdx.x >> 5;
  #pragma unroll
  for (int j = 0; j < 4; ++j)
    tile[ly + 8*j][lx] = in[(size_t)(r0 + ly + 8*j) * C + c0 + lx];
  __syncthreads();
  #pragma unroll
  for (int j = 0; j < 4; ++j)
    out[(size_t)(c0 + ly + 8*j) * R + r0 + lx] = tile[lx][ly + 8*j];
}

// ---------------- counting sort of batch rows by item_idx ----------------
__global__ __launch_bounds__(1024) void k_sort(const int* __restrict__ item_idx,
                                               int* __restrict__ perm) {
  __shared__ u32 cnt[N_ITEMS];     // 80 KB
  __shared__ u32 tsum[1024];
  int t = threadIdx.x;
  for (int i = t; i < N_ITEMS; i += 1024) cnt[i] = 0;
  __syncthreads();
  for (int b = t; b < HB; b += 1024) atomicAdd(&cnt[item_idx[b]], 1u);
  __syncthreads();
  u32 s = 0;
  int base = t * 20;
  for (int j = 0; j < 20; ++j) { int i = base + j; if (i < N_ITEMS) s += cnt[i]; }
  tsum[t] = s;
  __syncthreads();
  for (int off = 1; off < 1024; off <<= 1) {
    u32 v = (t >= off) ? tsum[t - off] : 0u;
    __syncthreads();
    tsum[t] += v;
    __syncthreads();
  }
  u32 run = tsum[t] - s;  // exclusive prefix
  for (int j = 0; j < 20; ++j) {
    int i = base + j;
    if (i < N_ITEMS) { u32 c = cnt[i]; cnt[i] = run; run += c; }
  }
  __syncthreads();
  for (int b = t; b < HB; b += 1024) {
    int v = item_idx[b];
    u32 pos = atomicAdd(&cnt[v], 1u);
    perm[pos] = b;
  }
}

// ---------------- packed-bit GEMM (bf16 MFMA, LUT unpack) ----------------
// blocks 0..255:  user mode, A rows from pk[user_idx[...]]
// blocks 256..511: item mode, A rows from pkT[item_idx[perm[...]]]
// tile 64(M) x 64(N), BK=64; 4 waves 2x2, wave = 32x32 via 16x16x32 MFMA.
__global__ __launch_bounds__(256) void k_gemm(
    const u32* __restrict__ pk, const u32* __restrict__ pkT,
    const int* __restrict__ user_idx, const int* __restrict__ item_idx,
    const int* __restrict__ perm,
    const u16* __restrict__ Wub, const u16* __restrict__ Wib,
    float* __restrict__ u0, float* __restrict__ ir) {
  __shared__ __attribute__((aligned(16))) u16 Bls[64 * 64];
  __shared__ __attribute__((aligned(16))) u32 lut4[256][4];
  __shared__ u32 pbase[64];
  __shared__ int prow[64];

  int bid = blockIdx.x;
  int mode_item = bid >> 8;
  int lid = bid & 255;
  int M0 = (lid >> 2) * 64;
  int N0 = (lid & 3) * 64;
  int tid = threadIdx.x;
  const u16* Wb = mode_item ? Wib : Wub;
  const u8* Pk = (const u8*)(mode_item ? pkT : pk);
  float* Cout = mode_item ? ir : u0;

  {  // byte -> 8 bf16 LUT (16 B/entry)
    u32 v = tid;
    lut4[tid][0] = ((v & 1u)   ? 0x3F80u : 0u) | ((v & 2u)   ? 0x3F800000u : 0u);
    lut4[tid][1] = ((v & 4u)   ? 0x3F80u : 0u) | ((v & 8u)   ? 0x3F800000u : 0u);
    lut4[tid][2] = ((v & 16u)  ? 0x3F80u : 0u) | ((v & 32u)  ? 0x3F800000u : 0u);
    lut4[tid][3] = ((v & 64u)  ? 0x3F80u : 0u) | ((v & 128u) ? 0x3F800000u : 0u);
  }
  if (tid < 64) {
    int s = M0 + tid;
    if (mode_item) { int p = perm[s]; prow[tid] = p; pbase[tid] = (u32)item_idx[p] * PKB; }
    else           { prow[tid] = s;   pbase[tid] = (u32)user_idx[s] * PKB; }
  }
  __syncthreads();

  f32x4 acc[2][2];
  #pragma unroll
  for (int a = 0; a < 2; ++a)
    #pragma unroll
    for (int b = 0; b < 2; ++b)
      #pragma unroll
      for (int j = 0; j < 4; ++j) acc[a][b][j] = 0.f;

  int lane = tid & 63, wave = tid >> 6;
  int WM = (wave >> 1) * 32;
  int WN = (wave & 1) * 32;
  int lrow = lane & 15;
  int lk8 = lane >> 4;            // 0..3 (8-elem k-subgroup)

  u32 pb0 = pbase[WM + lrow];
  u32 pb1 = pbase[WM + 16 + lrow];

  for (int k0 = 0; k0 < 20032; k0 += 64) {   // pads: pk/pkT words 625..631 are zero
    // ---- stage B: Bls[n][k] swizzled, 2 x b128 per thread ----
    #pragma unroll
    for (int i = 0; i < 2; ++i) {
      int id = tid + 256 * i;
      int n = id >> 3, c8 = id & 7;
      uint4 v = *(const uint4*)&Wb[(size_t)(N0 + n) * N_ITEMS + k0 + c8 * 8];
      int off = n * 64 + ((c8 * 8) ^ ((n & 7) << 3));
      *(uint4*)&Bls[off] = v;
    }
    // ---- A bytes (L3-resident packed bits) ----
    int bc = (k0 >> 3) + lk8;
    u8 b00 = Pk[pb0 + bc];
    u8 b01 = Pk[pb0 + bc + 4];
    u8 b10 = Pk[pb1 + bc];
    u8 b11 = Pk[pb1 + bc + 4];
    __syncthreads();
    bf16x8 af[2][2];
    af[0][0] = *(const bf16x8*)lut4[b00];
    af[0][1] = *(const bf16x8*)lut4[b01];
    af[1][0] = *(const bf16x8*)lut4[b10];
    af[1][1] = *(const bf16x8*)lut4[b11];
    #pragma unroll
    for (int kki = 0; kki < 2; ++kki) {
      int kk = kki * 32;
      bf16x8 bfr[2];
      #pragma unroll
      for (int fn = 0; fn < 2; ++fn) {
        int n = WN + fn * 16 + lrow;
        bfr[fn] = *(const bf16x8*)&Bls[n * 64 + ((kk + lk8 * 8) ^ ((n & 7) << 3))];
      }
      #pragma unroll
      for (int fm = 0; fm < 2; ++fm)
        #pragma unroll
        for (int fn = 0; fn < 2; ++fn)
          acc[fm][fn] = __builtin_amdgcn_mfma_f32_16x16x32_bf16(
              af[fm][kki], bfr[fn], acc[fm][fn], 0, 0, 0);
    }
    __syncthreads();
  }

  // ---- epilogue: C/D layout col=lane&15, row=(lane>>4)*4+j ----
  int crow0 = (lane >> 4) * 4;
  int ccol = lane & 15;
  #pragma unroll
  for (int fm = 0; fm < 2; ++fm)
    #pragma unroll
    for (int fn = 0; fn < 2; ++fn) {
      f32x4 v = acc[fm][fn];
      int col = N0 + WN + fn * 16 + ccol;
      #pragma unroll
      for (int j = 0; j < 4; ++j) {
        int rl = WM + fm * 16 + crow0 + j;
        Cout[(size_t)prow[rl] * H0 + col] = v[j];
      }
    }
}

// ---------------- fused correction + MLP + LN + logit ----------------
__global__ __launch_bounds__(256) void k_mlp(
    const u32* __restrict__ pk,
    const int* __restrict__ user_idx, const int* __restrict__ item_idx,
    const float* __restrict__ Wu, const float* __restrict__ Wi,
    const float* __restrict__ u0, const float* __restrict__ ir,
    const float* __restrict__ W1T, const float* __restrict__ b1,
    const float* __restrict__ g1, const float* __restrict__ be1,
    const float* __restrict__ W2T, const float* __restrict__ b2,
    const float* __restrict__ g2, const float* __restrict__ be2,
    const float* __restrict__ Wl, const float* __restrict__ bl,
    float* __restrict__ out) {
  __shared__ __attribute__((aligned(16))) float xl[16][H0];
  __shared__ __attribute__((aligned(16))) float h1l[16][H1];
  __shared__ int flagL[16], uL[16], iL[16];

  int tid = threadIdx.x, lane = tid & 63, wave = tid >> 6;
  int b0 = blockIdx.x * 16;

  if (tid < 16) {
    int b = b0 + tid;
    int uu = user_idx[b], ii = item_idx[b];
    uL[tid] = uu; iL[tid] = ii;
    u8 byte = ((const u8*)pk)[(size_t)uu * PKB + (ii >> 3)];
    flagL[tid] = (byte >> (ii & 7)) & 1;
  }
  __syncthreads();

  for (int idx = tid; idx < 16 * H0; idx += 256) {
    int rr = idx >> 8, h = idx & 255;
    float x = u0[(size_t)(b0 + rr) * H0 + h];
    if (flagL[rr]) x -= Wu[(size_t)h * N_ITEMS + iL[rr]];
    xl[rr][h] = x;
  }
  __syncthreads();

  float a0[16], a1[16];
  #pragma unroll
  for (int rr = 0; rr < 16; ++rr) { a0[rr] = 0.f; a1[rr] = 0.f; }
  for (int k4 = 0; k4 < H0 / 4; ++k4) {
    int k = k4 * 4;
    float w0a = W1T[(size_t)(k+0)*H1 + tid], w0b = W1T[(size_t)(k+0)*H1 + tid + 256];
    float w1a = W1T[(size_t)(k+1)*H1 + tid], w1b = W1T[(size_t)(k+1)*H1 + tid + 256];
    float w2a = W1T[(size_t)(k+2)*H1 + tid], w2b = W1T[(size_t)(k+2)*H1 + tid + 256];
    float w3a = W1T[(size_t)(k+3)*H1 + tid], w3b = W1T[(size_t)(k+3)*H1 + tid + 256];
    #pragma unroll
    for (int rr = 0; rr < 16; ++rr) {
      float4 x = *(const float4*)&xl[rr][k];
      a0[rr] += x.x * w0a + x.y * w1a + x.z * w2a + x.w * w3a;
      a1[rr] += x.x * w0b + x.y * w1b + x.z * w2b + x.w * w3b;
    }
  }
  #pragma unroll
  for (int rr = 0; rr < 16; ++rr) {
    h1l[rr][tid]       = a0[rr] + b1[tid];
    h1l[rr][tid + 256] = a1[rr] + b1[tid + 256];
  }
  __syncthreads();

  for (int rr = wave; rr < 16; rr += 4) {
    float s = 0.f;
    #pragma unroll
    for (int j = 0; j < 8; ++j) s += h1l[rr][lane + 64 * j];
    #pragma unroll
    for (int off = 32; off; off >>= 1) s += __shfl_xor(s, off);
    float m = s * (1.f / H1);
    float v = 0.f;
    #pragma unroll
    for (int j = 0; j < 8; ++j) { float d = h1l[rr][lane + 64*j] - m; v += d * d; }
    #pragma unroll
    for (int off = 32; off; off >>= 1) v += __shfl_xor(v, off);
    float inv = rsqrtf(v * (1.f / H1) + 1e-5f);
    #pragma unroll
    for (int j = 0; j < 8; ++j) {
      int o = lane + 64 * j;
      float y = (h1l[rr][o] - m) * inv * g1[o] + be1[o];
      h1l[rr][o] = fmaxf(y, 0.f);
    }
  }
  __syncthreads();

  float a2[16];
  #pragma unroll
  for (int rr = 0; rr < 16; ++rr) a2[rr] = 0.f;
  for (int k4 = 0; k4 < H1 / 4; ++k4) {
    int k = k4 * 4;
    float w0 = W2T[(size_t)(k+0)*H2 + tid];
    float w1 = W2T[(size_t)(k+1)*H2 + tid];
    float w2 = W2T[(size_t)(k+2)*H2 + tid];
    float w3 = W2T[(size_t)(k+3)*H2 + tid];
    #pragma unroll
    for (int rr = 0; rr < 16; ++rr) {
      float4 x = *(const float4*)&h1l[rr][k];
      a2[rr] += x.x * w0 + x.y * w1 + x.z * w2 + x.w * w3;
    }
  }
  __syncthreads();
  #pragma unroll
  for (int rr = 0; rr < 16; ++rr) xl[rr][tid] = a2[rr] + b2[tid];
  __syncthreads();

  for (int rr = wave; rr < 16; rr += 4) {
    float s = 0.f;
    #pragma unroll
    for (int j = 0; j < 4; ++j) s += xl[rr][lane + 64 * j];
    #pragma unroll
    for (int off = 32; off; off >>= 1) s += __shfl_xor(s, off);
    float m = s * (1.f / H2);
    float v = 0.f;
    #pragma unroll
    for (int j = 0; j < 4; ++j) { float d = xl[rr][lane + 64*j] - m; v += d * d; }
    #pragma unroll
    for (int off = 32; off; off >>= 1) v += __shfl_xor(v, off);
    float inv = rsqrtf(v * (1.f / H2) + 1e-5f);
    #pragma unroll
    for (int j = 0; j < 4; ++j) {
      int o = lane + 64 * j;
      float y = (xl[rr][o] - m) * inv * g2[o] + be2[o];
      xl[rr][o] = fmaxf(y, 0.f);
    }
  }
  __syncthreads();

  for (int rr = wave; rr < 16; rr += 4) {
    int b = b0 + rr;
    int flg = flagL[rr], uu = uL[rr];
    float s = 0.f;
    #pragma unroll
    for (int j = 0; j < 4; ++j) {
      int h = lane + 64 * j;
      float irv = ir[(size_t)b * H0 + h];
      if (flg) irv -= Wi[(size_t)h * N_USERS + uu];
      s += xl[rr][h] * irv * Wl[h];
    }
    #pragma unroll
    for (int off = 32; off; off >>= 1) s += __shfl_xor(s, off);
    if (lane == 0) out[b] = s + bl[0];
  }
}

extern "C" void kernel_launch(void* const* d_in, const int* in_sizes, int n_in,
                              void* d_out, int out_size, void* d_ws, size_t ws_size,
                              hipStream_t stream) {
  const int*   user_idx = (const int*)d_in[0];
  const int*   item_idx = (const int*)d_in[1];
  const u8*    inter    = (const u8*)d_in[2];
  const float* Wu  = (const float*)d_in[3];
  const float* Wi  = (const float*)d_in[4];
  const float* W1  = (const float*)d_in[5];
  const float* b1  = (const float*)d_in[6];
  const float* g1  = (const float*)d_in[7];
  const float* be1 = (const float*)d_in[8];
  const float* W2  = (const float*)d_in[9];
  const float* b2  = (const float*)d_in[10];
  const float* g2  = (const float*)d_in[11];
  const float* be2 = (const float*)d_in[12];
  const float* Wl  = (const float*)d_in[13];
  const float* bl  = (const float*)d_in[14];
  float* out = (float*)d_out;

  char* ws = (char*)d_ws;
  size_t off = 0;
  auto alloc = [&](size_t bytes) {
    size_t o = off;
    off = (off + bytes + 255) & ~(size_t)255;
    return o;
  };
  int*   flag = (int*)  (ws + alloc(4));
  u32*   pk   = (u32*)  (ws + alloc((size_t)N_USERS * PKB));
  u32*   pkT  = (u32*)  (ws + alloc((size_t)N_ITEMS * PKB));
  u16*   Wub  = (u16*)  (ws + alloc((size_t)H0 * N_ITEMS * 2));
  u16*   Wib  = (u16*)  (ws + alloc((size_t)H0 * N_USERS * 2));
  float* W1T  = (float*)(ws + alloc((size_t)H0 * H1 * 4));
  float* W2T  = (float*)(ws + alloc((size_t)H1 * H2 * 4));
  float* u0   = (float*)(ws + alloc((size_t)HB * H0 * 4));
  float* ir   = (float*)(ws + alloc((size_t)HB * H0 * 4));
  int*   perm = (int*)  (ws + alloc((size_t)HB * 4));

  k_detect<<<1, 256, 0, stream>>>(inter, flag);
  k_pack<0><<<50000, 256, 0, stream>>>(inter, pk, flag);
  k_pack<1><<<50000, 256, 0, stream>>>(inter, pk, flag);
  k_pack<2><<<50000, 256, 0, stream>>>(inter, pk, flag);
  k_bitT<<<1600, 256, 0, stream>>>(pk, pkT);
  k_convert<<<512, 256, 0, stream>>>(Wu, Wub, (H0 * N_ITEMS) / 4);
  k_convert<<<512, 256, 0, stream>>>(Wi, Wib, (H0 * N_USERS) / 4);
  k_transpose<<<(H1 / 32) * (H0 / 32), 256, 0, stream>>>(W1, W1T, H1, H0);
  k_transpose<<<(H2 / 32) * (H1 / 32), 256, 0, stream>>>(W2, W2T, H2, H1);
  k_sort<<<1, 1024, 0, stream>>>(item_idx, perm);
  k_gemm<<<512, 256, 0, stream>>>(pk, pkT, user_idx, item_idx, perm, Wub, Wib, u0, ir);
  k_mlp<<<256, 256, 0, stream>>>(pk, user_idx, item_idx, Wu, Wi, u0, ir,
                                 W1T, b1, g1, be1, W2T, b2, g2, be2, Wl, bl, out);
}

// Round 7
// 1004.468 us; speedup vs baseline: 3.9107x; 1.0477x over previous
//
#include <hip/hip_runtime.h>

#define N_USERS 20000
#define N_ITEMS 20000
#define NI1     20001      // row stride (elements) of interactions
#define HB      4096       // batch
#define H0      256
#define H1      512
#define H2      256
#define PKW     632        // u32 words per packed row (625 data + 7 zero pad)
#define PKB     (PKW*4)    // 2528 bytes per packed row

typedef unsigned short u16;
typedef unsigned char  u8;
typedef unsigned int   u32;
typedef unsigned long long u64;

typedef __attribute__((ext_vector_type(8))) __bf16 bf16x8;
typedef __attribute__((ext_vector_type(4))) float  f32x4;

__device__ __forceinline__ u16 f2bf(float f) {
  u32 u = __float_as_uint(f);
  u32 r = (u + 0x7FFFu + ((u >> 16) & 1u)) >> 16;   // RNE
  return (u16)r;
}

// ---------------- detect interactions element layout ----------------
// 0 = 1-byte bool, 1 = int32, 2 = float32 (classify by nonzero byte offsets)
__global__ __launch_bounds__(256) void k_detect(const u8* __restrict__ inter,
                                                int* __restrict__ flag) {
  __shared__ u32 cnt[4];
  if (threadIdx.x < 4) cnt[threadIdx.x] = 0;
  __syncthreads();
  u32 loc0 = 0, loc1 = 0, loc2 = 0, loc3 = 0;
  for (int i = threadIdx.x; i < 16384; i += 256) {   // 64 KB scan
    u32 w = ((const u32*)inter)[i];
    loc0 += (w & 0x000000FFu) ? 1u : 0u;
    loc1 += (w & 0x0000FF00u) ? 1u : 0u;
    loc2 += (w & 0x00FF0000u) ? 1u : 0u;
    loc3 += (w & 0xFF000000u) ? 1u : 0u;
  }
  atomicAdd(&cnt[0], loc0); atomicAdd(&cnt[1], loc1);
  atomicAdd(&cnt[2], loc2); atomicAdd(&cnt[3], loc3);
  __syncthreads();
  if (threadIdx.x == 0) {
    int lay;
    if (cnt[1] != 0)      lay = 0;   // bytes populated at offset1 -> u8 bool
    else if (cnt[0] != 0) lay = 1;   // only offset0 -> little-endian int32
    else                  lay = 2;   // offsets 2/3 only -> float32 (0x3F800000)
    *flag = lay;
  }
}

// ---------------- bit-pack interactions rows: pk[row][w] ----------------
template <int LAY>
__global__ __launch_bounds__(256) void k_pack(const u8* __restrict__ inter,
                                              u32* __restrict__ pk,
                                              const int* __restrict__ flag) {
  if (*flag != LAY) return;
  int wid = blockIdx.x * 4 + (threadIdx.x >> 6);
  int lane = threadIdx.x & 63;
  int row = wid / 10;
  int chunk = wid - row * 10;
  int w0 = chunk * 64;
  const u8* r8 = inter + (size_t)row * NI1 * (LAY == 0 ? 1 : 4);
  #pragma unroll 4
  for (int it = 0; it < 32; ++it) {
    int w = w0 + it * 2;
    int c = w * 32 + lane;
    bool p;
    if (LAY == 0) p = (c < N_ITEMS) && (r8[c] != 0);
    else          p = (c < N_ITEMS) && (((const u32*)r8)[c] != 0u);
    u64 m = __ballot(p);
    if (lane == 0 && w < PKW)
      *(u64*)&pk[(size_t)row * PKW + w] = m;
  }
}

// ---------------- bit transpose: pkT[c][v] bit j = pk[v*32+j] bit c ----------------
#define HDSTEP(J, M)                                      \
  _Pragma("unroll")                                       \
  for (int k = 0; k < 32; ++k) if (!(k & J)) {            \
    u32 tt = (a[k] ^ (a[k | J] >> J)) & M;                \
    a[k] ^= tt; a[k | J] ^= tt << J;                      \
  }

__global__ __launch_bounds__(256) void k_bitT(const u32* __restrict__ pk,
                                              u32* __restrict__ pkT) {
  __shared__ u32 in_l[512][17];
  __shared__ u32 out_l[32][16][17];   // [i][lw_p][lr_p] -> bank-safe store phase
  int t = threadIdx.x;
  int vt = blockIdx.x % 40, wt = blockIdx.x / 40;
  int v0 = vt * 16, wc0 = wt * 16;
  int lw = t & 15, lr = t >> 4;
  for (int ch = 0; ch < 32; ++ch) {
    int rloc = ch * 16 + lr;
    int R = v0 * 32 + rloc;
    int W = wc0 + lw;
    u32 val = 0;
    if (R < N_USERS && W < PKW) val = pk[(size_t)R * PKW + W];
    in_l[rloc][lw] = val;
  }
  __syncthreads();
  u32 a[32];
  #pragma unroll
  for (int j = 0; j < 32; ++j) a[j] = in_l[lr * 32 + j][lw];
  HDSTEP(16, 0x0000FFFFu)
  HDSTEP(8,  0x00FF00FFu)
  HDSTEP(4,  0x0F0F0F0Fu)
  HDSTEP(2,  0x33333333u)
  HDSTEP(1,  0x55555555u)
  // thread (lw,lr): holds output rows lw*32+i, column word v0+lr
  #pragma unroll
  for (int i = 0; i < 32; ++i) out_l[i][lw][lr] = __brev(a[31 - i]);
  __syncthreads();
  for (int ch = 0; ch < 32; ++ch) {
    int rloc = ch * 16 + lr;
    int C = wc0 * 32 + rloc;
    int V = v0 + lw;
    if (C < N_ITEMS && V < PKW)
      pkT[(size_t)C * PKW + V] = out_l[rloc & 31][rloc >> 5][lw];
  }
}

// ---------------- f32 -> bf16 copy-convert (keeps layout) ----------------
__global__ __launch_bounds__(256) void k_convert(const float* __restrict__ in,
                                                 u16* __restrict__ out, int n4) {
  int idx = blockIdx.x * 256 + threadIdx.x;
  int stride = gridDim.x * 256;
  for (int i = idx; i < n4; i += stride) {
    float4 v = ((const float4*)in)[i];
    u64 p = (u64)f2bf(v.x) | ((u64)f2bf(v.y) << 16) |
            ((u64)f2bf(v.z) << 32) | ((u64)f2bf(v.w) << 48);
    ((u64*)out)[i] = p;
  }
}

// ---------------- f32 transpose: in (R,C) -> out (C,R) ----------------
__global__ __launch_bounds__(256) void k_transpose(const float* __restrict__ in,
                                                   float* __restrict__ out,
                                                   int R, int C) {
  __shared__ float tile[32][33];
  int nbx = C >> 5;
  int bx = blockIdx.x % nbx, by = blockIdx.x / nbx;
  int c0 = bx * 32, r0 = by * 32;
  int lx = threadIdx.x & 31, ly = threadIdx.x >> 5;
  #pragma unroll
  for (int j = 0; j < 4; ++j)
    tile[ly + 8*j][lx] = in[(size_t)(r0 + ly + 8*j) * C + c0 + lx];
  __syncthreads();
  #pragma unroll
  for (int j = 0; j < 4; ++j)
    out[(size_t)(c0 + ly + 8*j) * R + r0 + lx] = tile[lx][ly + 8*j];
}

// ---------------- counting sort of batch rows by item_idx ----------------
__global__ __launch_bounds__(1024) void k_sort(const int* __restrict__ item_idx,
                                               int* __restrict__ perm) {
  __shared__ u32 cnt[N_ITEMS];     // 80 KB
  __shared__ u32 tsum[1024];
  int t = threadIdx.x;
  for (int i = t; i < N_ITEMS; i += 1024) cnt[i] = 0;
  __syncthreads();
  for (int b = t; b < HB; b += 1024) atomicAdd(&cnt[item_idx[b]], 1u);
  __syncthreads();
  u32 s = 0;
  int base = t * 20;
  for (int j = 0; j < 20; ++j) { int i = base + j; if (i < N_ITEMS) s += cnt[i]; }
  tsum[t] = s;
  __syncthreads();
  for (int off = 1; off < 1024; off <<= 1) {
    u32 v = (t >= off) ? tsum[t - off] : 0u;
    __syncthreads();
    tsum[t] += v;
    __syncthreads();
  }
  u32 run = tsum[t] - s;  // exclusive prefix
  for (int j = 0; j < 20; ++j) {
    int i = base + j;
    if (i < N_ITEMS) { u32 c = cnt[i]; cnt[i] = run; run += c; }
  }
  __syncthreads();
  for (int b = t; b < HB; b += 1024) {
    int v = item_idx[b];
    u32 pos = atomicAdd(&cnt[v], 1u);
    perm[pos] = b;
  }
}

// ---------------- packed-bit GEMM (bf16 MFMA, nibble-LUT unpack) ----------------
// blocks 0..255:  user mode, A rows from pk[user_idx[...]]
// blocks 256..511: item mode, A rows from pkT[item_idx[perm[...]]]
// tile 64(M) x 64(N), BK=128; 4 waves 2x2, wave = 32x32 via 16x16x32 MFMA.
__global__ __launch_bounds__(256) void k_gemm(
    const u32* __restrict__ pk, const u32* __restrict__ pkT,
    const int* __restrict__ user_idx, const int* __restrict__ item_idx,
    const int* __restrict__ perm,
    const u16* __restrict__ Wub, const u16* __restrict__ Wib,
    float* __restrict__ u0, float* __restrict__ ir) {
  __shared__ __attribute__((aligned(16))) u16 Bls[64 * 128];   // 16 KB
  __shared__ __attribute__((aligned(16))) uint2 lut8[16];      // nibble -> 4 bf16
  __shared__ u32 pbase[64];
  __shared__ int prow[64];

  int bid = blockIdx.x;
  int mode_item = bid >> 8;
  int lid = bid & 255;
  int M0 = (lid >> 2) * 64;
  int N0 = (lid & 3) * 64;
  int tid = threadIdx.x;
  const u16* Wb = mode_item ? Wib : Wub;
  const u8* Pk = (const u8*)(mode_item ? pkT : pk);
  float* Cout = mode_item ? ir : u0;

  if (tid < 16) {
    u32 v = tid;
    lut8[tid].x = ((v & 1u) ? 0x3F80u : 0u) | ((v & 2u) ? 0x3F800000u : 0u);
    lut8[tid].y = ((v & 4u) ? 0x3F80u : 0u) | ((v & 8u) ? 0x3F800000u : 0u);
  }
  if (tid < 64) {
    int s = M0 + tid;
    if (mode_item) { int p = perm[s]; prow[tid] = p; pbase[tid] = (u32)item_idx[p] * PKB; }
    else           { prow[tid] = s;   pbase[tid] = (u32)user_idx[s] * PKB; }
  }
  __syncthreads();

  f32x4 acc[2][2];
  #pragma unroll
  for (int a = 0; a < 2; ++a)
    #pragma unroll
    for (int b = 0; b < 2; ++b)
      #pragma unroll
      for (int j = 0; j < 4; ++j) acc[a][b][j] = 0.f;

  int lane = tid & 63, wave = tid >> 6;
  int WM = (wave >> 1) * 32;
  int WN = (wave & 1) * 32;
  int lrow = lane & 15;
  int lk8 = lane >> 4;            // 0..3
  int sh = lk8 * 8;

  u32 pb0 = pbase[WM + lrow];
  u32 pb1 = pbase[WM + 16 + lrow];

  for (int k0 = 0; k0 < 20096; k0 += 128) {   // 157 iters; bits >=20000 are zero
    // ---- stage B: Bls[n][k] swizzled, 4 x b128 per thread ----
    #pragma unroll
    for (int i = 0; i < 4; ++i) {
      int id = tid + 256 * i;
      int n = id >> 4, c8 = id & 15;
      int k = k0 + c8 * 8;
      uint4 v = make_uint4(0u, 0u, 0u, 0u);
      if (k < N_ITEMS) v = *(const uint4*)&Wb[(size_t)(N0 + n) * N_ITEMS + k];
      int off = n * 128 + ((c8 * 8) ^ ((n & 7) << 3));
      *(uint4*)&Bls[off] = v;
    }
    // ---- A bits: one aligned uint4 per row (128 k-bits) ----
    uint4 qa0 = *(const uint4*)(Pk + pb0 + (k0 >> 3));
    uint4 qa1 = *(const uint4*)(Pk + pb1 + (k0 >> 3));
    u32 qw0[4] = {qa0.x, qa0.y, qa0.z, qa0.w};
    u32 qw1[4] = {qa1.x, qa1.y, qa1.z, qa1.w};
    __syncthreads();
    #pragma unroll
    for (int kki = 0; kki < 4; ++kki) {
      u32 b0 = (qw0[kki] >> sh) & 0xFFu;
      u32 b1 = (qw1[kki] >> sh) & 0xFFu;
      union { u32 w[4]; bf16x8 v; } a0, a1;
      uint2 l0 = lut8[b0 & 15u], h0 = lut8[b0 >> 4];
      uint2 l1 = lut8[b1 & 15u], h1 = lut8[b1 >> 4];
      a0.w[0] = l0.x; a0.w[1] = l0.y; a0.w[2] = h0.x; a0.w[3] = h0.y;
      a1.w[0] = l1.x; a1.w[1] = l1.y; a1.w[2] = h1.x; a1.w[3] = h1.y;
      bf16x8 bfr[2];
      #pragma unroll
      for (int fn = 0; fn < 2; ++fn) {
        int n = WN + fn * 16 + lrow;
        bfr[fn] = *(const bf16x8*)&Bls[n * 128 + ((kki * 32 + sh) ^ ((n & 7) << 3))];
      }
      acc[0][0] = __builtin_amdgcn_mfma_f32_16x16x32_bf16(a0.v, bfr[0], acc[0][0], 0, 0, 0);
      acc[0][1] = __builtin_amdgcn_mfma_f32_16x16x32_bf16(a0.v, bfr[1], acc[0][1], 0, 0, 0);
      acc[1][0] = __builtin_amdgcn_mfma_f32_16x16x32_bf16(a1.v, bfr[0], acc[1][0], 0, 0, 0);
      acc[1][1] = __builtin_amdgcn_mfma_f32_16x16x32_bf16(a1.v, bfr[1], acc[1][1], 0, 0, 0);
    }
    __syncthreads();
  }

  // ---- epilogue: C/D layout col=lane&15, row=(lane>>4)*4+j ----
  int crow0 = (lane >> 4) * 4;
  int ccol = lane & 15;
  #pragma unroll
  for (int fm = 0; fm < 2; ++fm)
    #pragma unroll
    for (int fn = 0; fn < 2; ++fn) {
      f32x4 v = acc[fm][fn];
      int col = N0 + WN + fn * 16 + ccol;
      #pragma unroll
      for (int j = 0; j < 4; ++j) {
        int rl = WM + fm * 16 + crow0 + j;
        Cout[(size_t)prow[rl] * H0 + col] = v[j];
      }
    }
}

// ---------------- fused correction + MLP + LN + logit ----------------
__global__ __launch_bounds__(256) void k_mlp(
    const u32* __restrict__ pk,
    const int* __restrict__ user_idx, const int* __restrict__ item_idx,
    const float* __restrict__ Wu, const float* __restrict__ Wi,
    const float* __restrict__ u0, const float* __restrict__ ir,
    const float* __restrict__ W1T, const float* __restrict__ b1,
    const float* __restrict__ g1, const float* __restrict__ be1,
    const float* __restrict__ W2T, const float* __restrict__ b2,
    const float* __restrict__ g2, const float* __restrict__ be2,
    const float* __restrict__ Wl, const float* __restrict__ bl,
    float* __restrict__ out) {
  __shared__ __attribute__((aligned(16))) float xl[16][H0];
  __shared__ __attribute__((aligned(16))) float h1l[16][H1];
  __shared__ int flagL[16], uL[16], iL[16];

  int tid = threadIdx.x, lane = tid & 63, wave = tid >> 6;
  int b0 = blockIdx.x * 16;

  if (tid < 16) {
    int b = b0 + tid;
    int uu = user_idx[b], ii = item_idx[b];
    uL[tid] = uu; iL[tid] = ii;
    u8 byte = ((const u8*)pk)[(size_t)uu * PKB + (ii >> 3)];
    flagL[tid] = (byte >> (ii & 7)) & 1;
  }
  __syncthreads();

  for (int idx = tid; idx < 16 * H0; idx += 256) {
    int rr = idx >> 8, h = idx & 255;
    float x = u0[(size_t)(b0 + rr) * H0 + h];
    if (flagL[rr]) x -= Wu[(size_t)h * N_ITEMS + iL[rr]];
    xl[rr][h] = x;
  }
  __syncthreads();

  float a0[16], a1[16];
  #pragma unroll
  for (int rr = 0; rr < 16; ++rr) { a0[rr] = 0.f; a1[rr] = 0.f; }
  for (int k4 = 0; k4 < H0 / 4; ++k4) {
    int k = k4 * 4;
    float w0a = W1T[(size_t)(k+0)*H1 + tid], w0b = W1T[(size_t)(k+0)*H1 + tid + 256];
    float w1a = W1T[(size_t)(k+1)*H1 + tid], w1b = W1T[(size_t)(k+1)*H1 + tid + 256];
    float w2a = W1T[(size_t)(k+2)*H1 + tid], w2b = W1T[(size_t)(k+2)*H1 + tid + 256];
    float w3a = W1T[(size_t)(k+3)*H1 + tid], w3b = W1T[(size_t)(k+3)*H1 + tid + 256];
    #pragma unroll
    for (int rr = 0; rr < 16; ++rr) {
      float4 x = *(const float4*)&xl[rr][k];
      a0[rr] += x.x * w0a + x.y * w1a + x.z * w2a + x.w * w3a;
      a1[rr] += x.x * w0b + x.y * w1b + x.z * w2b + x.w * w3b;
    }
  }
  #pragma unroll
  for (int rr = 0; rr < 16; ++rr) {
    h1l[rr][tid]       = a0[rr] + b1[tid];
    h1l[rr][tid + 256] = a1[rr] + b1[tid + 256];
  }
  __syncthreads();

  for (int rr = wave; rr < 16; rr += 4) {
    float s = 0.f;
    #pragma unroll
    for (int j = 0; j < 8; ++j) s += h1l[rr][lane + 64 * j];
    #pragma unroll
    for (int off = 32; off; off >>= 1) s += __shfl_xor(s, off);
    float m = s * (1.f / H1);
    float v = 0.f;
    #pragma unroll
    for (int j = 0; j < 8; ++j) { float d = h1l[rr][lane + 64*j] - m; v += d * d; }
    #pragma unroll
    for (int off = 32; off; off >>= 1) v += __shfl_xor(v, off);
    float inv = rsqrtf(v * (1.f / H1) + 1e-5f);
    #pragma unroll
    for (int j = 0; j < 8; ++j) {
      int o = lane + 64 * j;
      float y = (h1l[rr][o] - m) * inv * g1[o] + be1[o];
      h1l[rr][o] = fmaxf(y, 0.f);
    }
  }
  __syncthreads();

  float a2[16];
  #pragma unroll
  for (int rr = 0; rr < 16; ++rr) a2[rr] = 0.f;
  for (int k4 = 0; k4 < H1 / 4; ++k4) {
    int k = k4 * 4;
    float w0 = W2T[(size_t)(k+0)*H2 + tid];
    float w1 = W2T[(size_t)(k+1)*H2 + tid];
    float w2 = W2T[(size_t)(k+2)*H2 + tid];
    float w3 = W2T[(size_t)(k+3)*H2 + tid];
    #pragma unroll
    for (int rr = 0; rr < 16; ++rr) {
      float4 x = *(const float4*)&h1l[rr][k];
      a2[rr] += x.x * w0 + x.y * w1 + x.z * w2 + x.w * w3;
    }
  }
  __syncthreads();
  #pragma unroll
  for (int rr = 0; rr < 16; ++rr) xl[rr][tid] = a2[rr] + b2[tid];
  __syncthreads();

  for (int rr = wave; rr < 16; rr += 4) {
    float s = 0.f;
    #pragma unroll
    for (int j = 0; j < 4; ++j) s += xl[rr][lane + 64 * j];
    #pragma unroll
    for (int off = 32; off; off >>= 1) s += __shfl_xor(s, off);
    float m = s * (1.f / H2);
    float v = 0.f;
    #pragma unroll
    for (int j = 0; j < 4; ++j) { float d = xl[rr][lane + 64*j] - m; v += d * d; }
    #pragma unroll
    for (int off = 32; off; off >>= 1) v += __shfl_xor(v, off);
    float inv = rsqrtf(v * (1.f / H2) + 1e-5f);
    #pragma unroll
    for (int j = 0; j < 4; ++j) {
      int o = lane + 64 * j;
      float y = (xl[rr][o] - m) * inv * g2[o] + be2[o];
      xl[rr][o] = fmaxf(y, 0.f);
    }
  }
  __syncthreads();

  for (int rr = wave; rr < 16; rr += 4) {
    int b = b0 + rr;
    int flg = flagL[rr], uu = uL[rr];
    float s = 0.f;
    #pragma unroll
    for (int j = 0; j < 4; ++j) {
      int h = lane + 64 * j;
      float irv = ir[(size_t)b * H0 + h];
      if (flg) irv -= Wi[(size_t)h * N_USERS + uu];
      s += xl[rr][h] * irv * Wl[h];
    }
    #pragma unroll
    for (int off = 32; off; off >>= 1) s += __shfl_xor(s, off);
    if (lane == 0) out[b] = s + bl[0];
  }
}

extern "C" void kernel_launch(void* const* d_in, const int* in_sizes, int n_in,
                              void* d_out, int out_size, void* d_ws, size_t ws_size,
                              hipStream_t stream) {
  const int*   user_idx = (const int*)d_in[0];
  const int*   item_idx = (const int*)d_in[1];
  const u8*    inter    = (const u8*)d_in[2];
  const float* Wu  = (const float*)d_in[3];
  const float* Wi  = (const float*)d_in[4];
  const float* W1  = (const float*)d_in[5];
  const float* b1  = (const float*)d_in[6];
  const float* g1  = (const float*)d_in[7];
  const float* be1 = (const float*)d_in[8];
  const float* W2  = (const float*)d_in[9];
  const float* b2  = (const float*)d_in[10];
  const float* g2  = (const float*)d_in[11];
  const float* be2 = (const float*)d_in[12];
  const float* Wl  = (const float*)d_in[13];
  const float* bl  = (const float*)d_in[14];
  float* out = (float*)d_out;

  char* ws = (char*)d_ws;
  size_t off = 0;
  auto alloc = [&](size_t bytes) {
    size_t o = off;
    off = (off + bytes + 255) & ~(size_t)255;
    return o;
  };
  int*   flag = (int*)  (ws + alloc(4));
  u32*   pk   = (u32*)  (ws + alloc((size_t)N_USERS * PKB));
  u32*   pkT  = (u32*)  (ws + alloc((size_t)N_ITEMS * PKB));
  u16*   Wub  = (u16*)  (ws + alloc((size_t)H0 * N_ITEMS * 2));
  u16*   Wib  = (u16*)  (ws + alloc((size_t)H0 * N_USERS * 2));
  float* W1T  = (float*)(ws + alloc((size_t)H0 * H1 * 4));
  float* W2T  = (float*)(ws + alloc((size_t)H1 * H2 * 4));
  float* u0   = (float*)(ws + alloc((size_t)HB * H0 * 4));
  float* ir   = (float*)(ws + alloc((size_t)HB * H0 * 4));
  int*   perm = (int*)  (ws + alloc((size_t)HB * 4));

  k_detect<<<1, 256, 0, stream>>>(inter, flag);
  k_pack<0><<<50000, 256, 0, stream>>>(inter, pk, flag);
  k_pack<1><<<50000, 256, 0, stream>>>(inter, pk, flag);
  k_pack<2><<<50000, 256, 0, stream>>>(inter, pk, flag);
  k_bitT<<<1600, 256, 0, stream>>>(pk, pkT);
  k_convert<<<512, 256, 0, stream>>>(Wu, Wub, (H0 * N_ITEMS) / 4);
  k_convert<<<512, 256, 0, stream>>>(Wi, Wib, (H0 * N_USERS) / 4);
  k_transpose<<<(H1 / 32) * (H0 / 32), 256, 0, stream>>>(W1, W1T, H1, H0);
  k_transpose<<<(H2 / 32) * (H1 / 32), 256, 0, stream>>>(W2, W2T, H2, H1);
  k_sort<<<1, 1024, 0, stream>>>(item_idx, perm);
  k_gemm<<<512, 256, 0, stream>>>(pk, pkT, user_idx, item_idx, perm, Wub, Wib, u0, ir);
  k_mlp<<<256, 256, 0, stream>>>(pk, user_idx, item_idx, Wu, Wi, u0, ir,
                                 W1T, b1, g1, be1, W2T, b2, g2, be2, Wl, bl, out);
}